// Round 11
// baseline (52.653 us; speedup 1.0000x reference)
//
#include <hip/hip_runtime.h>
#include <cstdint>

typedef unsigned long long u64;
typedef float f4 __attribute__((ext_vector_type(4)));

constexpr int S   = 160;          // D = H = W
constexpr int NB  = 4;            // batches
constexpr int PAD = 8;            // d/h padding in the global bit buffer
constexpr int SP  = S + 2 * PAD;  // 176
constexpr int BUFW = NB * SP * 3 * SP;     // u64 per buffer (371,712)
constexpr int BLKC = 512;                  // tile kernel block size

__device__ __forceinline__ int widx(int b, int dp, int w, int hp) {
  return ((b * SP + dp) * 3 + w) * SP + hp;
}

// ---------------- full-row (3 u64 = 192 bits, k in [0,160)) helpers ----------------
struct R3 { u64 a, b, c; };

template <bool OR_> __device__ __forceinline__ u64 rop(u64 x, u64 y) { return OR_ ? (x | y) : (x & y); }
template <bool OR_> __device__ __forceinline__ R3 rop3(R3 x, R3 y) {
  return {rop<OR_>(x.a, y.a), rop<OR_>(x.b, y.b), rop<OR_>(x.c, y.c)};
}
template <int N> __device__ __forceinline__ R3 sl3(R3 x) {
  return {x.a << N, (x.b << N) | (x.a >> (64 - N)), (x.c << N) | (x.b >> (64 - N))};
}
template <int N> __device__ __forceinline__ R3 sr3(R3 x) {
  return {(x.a >> N) | (x.b << (64 - N)), (x.b >> N) | (x.c << (64 - N)), x.c >> N};
}
template <bool OR_> __device__ __forceinline__ R3 e1(R3 x) {
  return rop3<OR_>(rop3<OR_>(x, sl3<1>(x)), sr3<1>(x));
}
__device__ __forceinline__ R3 ldr(const u64* p) { return {p[0], p[1], p[2]}; }

__device__ __forceinline__ u64 squash(u64 x) {  // 8 bytes of nibbles -> 32 bits
  x = (x | (x >> 4))  & 0x00FF00FF00FF00FFull;
  x = (x | (x >> 8))  & 0x0000FFFF0000FFFFull;
  x = (x | (x >> 16)) & 0x00000000FFFFFFFFull;
  return x;
}

// ================= kernel 1: pack + P1 of chain 1 (per (b,d) slice, zero halo) =================
// P1 (jk-plane): |dj|<=4 -> k±6 ; |dj|=5 -> ±5 ; |dj|=6 -> ±4
template <bool OR_>
__device__ void p1_slice(const u64* __restrict__ bits, u64* __restrict__ dstA, int b, int d) {
  for (int hh = threadIdx.x; hh < S; hh += 256) {
    const u64* base = bits + (hh + 6) * 3;
    R3 G1 = ldr(base - 4 * 3);
#pragma unroll
    for (int r = -3; r <= 4; ++r) G1 = rop3<OR_>(G1, ldr(base + r * 3));
    R3 G2 = rop3<OR_>(ldr(base - 5 * 3), ldr(base + 5 * 3));
    R3 G3 = rop3<OR_>(ldr(base - 6 * 3), ldr(base + 6 * 3));
    R3 X = rop3<OR_>(rop3<OR_>(e1<OR_>(e1<OR_>(G1)), e1<OR_>(G2)), G3);
    R3 y = e1<OR_>(X);
    R3 Rr = rop3<OR_>(rop3<OR_>(y, sl3<3>(y)), sr3<3>(y));
    Rr.c &= 0xFFFFFFFFull;
    dstA[widx(b, d + PAD, 0, hh + PAD)] = Rr.a;
    dstA[widx(b, d + PAD, 1, hh + PAD)] = Rr.b;
    dstA[widx(b, d + PAD, 2, hh + PAD)] = Rr.c;
  }
}

__global__ __launch_bounds__(256) void packp1_k(const float* __restrict__ aux,
                                                const float* __restrict__ inp,
                                                u64* __restrict__ bufA,
                                                u64* __restrict__ bufB) {
  __shared__ unsigned char nib[160][48];
  __shared__ u64 bits[172 * 3];              // h rows -6..165 (6-row zero aprons)
  const int blk = blockIdx.x;
  const int b = blk / S, d = blk % S;
  const int tid = threadIdx.x;

  // zero pad halos of both buffers (grid-stride; disjoint from all interior writes)
  for (int g = blk * 256 + tid; g < BUFW; g += 640 * 256) {
    const int hp = g % SP;
    const int dp = (g / (SP * 3)) % SP;
    if ((dp < PAD) | (dp >= S + PAD) | (hp < PAD) | (hp >= S + PAD)) { bufA[g] = 0ull; bufB[g] = 0ull; }
  }

  // zero bits aprons (rows 0..5, 166..171) and nib pad columns 40..47
  for (int i = tid; i < 36; i += 256) {
    const int r = i / 3, w = i % 3;
    const int row = (r < 6) ? r : 160 + r;
    bits[row * 3 + w] = 0ull;
  }
  for (int i = tid; i < 160 * 8; i += 256) nib[i >> 3][40 + (i & 7)] = 0;

  // pack this (b,d) slice: 6400 contiguous f4 (102.4 KB), fully coalesced
  const f4* srcp = reinterpret_cast<const f4*>(aux) + (size_t)(b * S + d) * 6400;
  const size_t eb0 = (size_t)(b * S + d) * 25600;
  for (int i = tid; i < 6400; i += 256) {
    const f4 a = __builtin_nontemporal_load(srcp + i);
    unsigned n = 0;
    if (a.x < 0.0f) n |= 1u; else if (a.x == 0.0f) { if (inp[eb0 + i * 4 + 0] != 0.0f) n |= 1u; }
    if (a.y < 0.0f) n |= 2u; else if (a.y == 0.0f) { if (inp[eb0 + i * 4 + 1] != 0.0f) n |= 2u; }
    if (a.z < 0.0f) n |= 4u; else if (a.z == 0.0f) { if (inp[eb0 + i * 4 + 2] != 0.0f) n |= 4u; }
    if (a.w < 0.0f) n |= 8u; else if (a.w == 0.0f) { if (inp[eb0 + i * 4 + 3] != 0.0f) n |= 8u; }
    nib[i / 40][i % 40] = (unsigned char)n;
  }
  __syncthreads();
  for (int t = tid; t < 480; t += 256) {
    const int row = t / 3, w = t % 3;
    const u64 x0 = *reinterpret_cast<const u64*>(&nib[row][w * 16]);
    const u64 x1 = *reinterpret_cast<const u64*>(&nib[row][w * 16 + 8]);
    bits[(row + 6) * 3 + w] = squash(x0) | (squash(x1) << 32);
  }
  __syncthreads();

  if ((b & 1) == 0) p1_slice<true >(bits, bufA, b, d);   // chain1: even batch = dilate(OR)
  else              p1_slice<false>(bits, bufA, b, d);
}

// ================= kernel 2: P2 + P3 of chain 1 (16x16 tile, IN 32x20) =================
// P2 (ik-plane): |di|<=4 -> k±2 ; |di|=5 -> ±1 ; |di|=6 -> 0
// P3 (ij-diamond): (0,0),(±1,±1),(±2,0),(0,±2)
template <bool OR_>
__device__ void p23_body(const u64* __restrict__ src, u64* __restrict__ dst,
                         int b, int d0, int h0, u64* sIN, u64* sT2) {
  // IN: d rows d0-8..d0+23 (di 0..31), h cols h0-2..h0+17 (hi 0..19)
  for (int i = threadIdx.x; i < 32 * 20 * 3; i += BLKC) {
    const int hi = i % 20, w = (i / 20) % 3, di = i / 60;
    sIN[(di * 20 + hi) * 3 + w] = src[widx(b, d0 + di, w, h0 + hi + 6)];
  }
  __syncthreads();

  // P2: out d:[-2..17] x h:[-2..17] -> T2[20][20]; IN d-row = dd + r, r in [0..12], center 6
  for (int s = threadIdx.x; s < 20 * 20; s += BLKC) {
    const int dd = s / 20, hh = s % 20;
    const u64* base = sIN + (dd * 20 + hh) * 3;   // d-row stride = 60 u64
    R3 G1 = ldr(base + 2 * 60);
#pragma unroll
    for (int r = 3; r <= 10; ++r) G1 = rop3<OR_>(G1, ldr(base + r * 60));
    R3 G2 = rop3<OR_>(ldr(base + 1 * 60), ldr(base + 11 * 60));
    R3 G3 = rop3<OR_>(ldr(base + 0 * 60), ldr(base + 12 * 60));
    R3 X = rop3<OR_>(e1<OR_>(rop3<OR_>(e1<OR_>(G1), G2)), G3);
    X.c &= 0xFFFFFFFFull;
    u64* q = sT2 + s * 3; q[0] = X.a; q[1] = X.b; q[2] = X.c;
  }
  __syncthreads();

  // P3: final 16x16 -> dst bits
  if (threadIdx.x < 256) {
    const int dd = threadIdx.x >> 4, hh = threadIdx.x & 15;
    const u64* t2 = sT2 + ((dd + 2) * 20 + (hh + 2)) * 3;
    R3 A = ldr(t2);
    A = rop3<OR_>(A, ldr(t2 + 21 * 3)); A = rop3<OR_>(A, ldr(t2 + 19 * 3));
    A = rop3<OR_>(A, ldr(t2 - 19 * 3)); A = rop3<OR_>(A, ldr(t2 - 21 * 3));
    A = rop3<OR_>(A, ldr(t2 + 40 * 3)); A = rop3<OR_>(A, ldr(t2 - 40 * 3));
    A = rop3<OR_>(A, ldr(t2 + 2 * 3));  A = rop3<OR_>(A, ldr(t2 - 2 * 3));
    A.c &= 0xFFFFFFFFull;
    dst[widx(b, d0 + dd + PAD, 0, h0 + hh + PAD)] = A.a;
    dst[widx(b, d0 + dd + PAD, 1, h0 + hh + PAD)] = A.b;
    dst[widx(b, d0 + dd + PAD, 2, h0 + hh + PAD)] = A.c;
  }
}

__global__ __launch_bounds__(BLKC) void p23_k(const u64* __restrict__ src,
                                              u64* __restrict__ dst) {
  __shared__ u64 sIN[32 * 20 * 3];   // 15,360 B
  __shared__ u64 sT2[20 * 20 * 3];   //  9,600 B
  const int blk = blockIdx.x;
  const int b = blk / 100, tile = blk % 100;
  const int d0 = (tile / 10) * 16, h0 = (tile % 10) * 16;
  if ((b & 1) == 0) p23_body<true >(src, dst, b, d0, h0, sIN, sT2);
  else              p23_body<false>(src, dst, b, d0, h0, sIN, sT2);
}

// ================= kernel 3: chain 2 (P1'P2'P3') + unpack — R6-verified =================
template <bool OR_>
__device__ void chain_body(const u64* __restrict__ src, float* __restrict__ out,
                           int b, int d0, int h0, u64* sIN, u64* sT1, u64* sT2) {
  for (int i = threadIdx.x; i < 32 * 32 * 3; i += BLKC) {
    const int hi = i % 32, w = (i / 32) % 3, di = i / 96;
    sIN[(di * 32 + hi) * 3 + w] = src[widx(b, d0 + di, w, h0 + hi)];
  }
  __syncthreads();

  for (int s = threadIdx.x; s < 32 * 20; s += BLKC) {
    const int dd = s / 20, hh = s % 20;
    const u64* base = sIN + (dd * 32 + hh) * 3;
    R3 G1 = ldr(base + 2 * 3);
#pragma unroll
    for (int r = 3; r <= 10; ++r) G1 = rop3<OR_>(G1, ldr(base + r * 3));
    R3 G2 = rop3<OR_>(ldr(base + 1 * 3), ldr(base + 11 * 3));
    R3 G3 = rop3<OR_>(ldr(base + 0 * 3), ldr(base + 12 * 3));
    R3 X = rop3<OR_>(rop3<OR_>(e1<OR_>(e1<OR_>(G1)), e1<OR_>(G2)), G3);
    R3 y = e1<OR_>(X);
    R3 R = rop3<OR_>(rop3<OR_>(y, sl3<3>(y)), sr3<3>(y));
    R.c &= 0xFFFFFFFFull;
    u64* q = sT1 + s * 3; q[0] = R.a; q[1] = R.b; q[2] = R.c;
  }
  __syncthreads();

  for (int s = threadIdx.x; s < 20 * 20; s += BLKC) {
    const int dd = s / 20, hh = s % 20;
    const u64* base = sT1 + (dd * 20 + hh) * 3;
    R3 G1 = ldr(base + 2 * 60);
#pragma unroll
    for (int r = 3; r <= 10; ++r) G1 = rop3<OR_>(G1, ldr(base + r * 60));
    R3 G2 = rop3<OR_>(ldr(base + 1 * 60), ldr(base + 11 * 60));
    R3 G3 = rop3<OR_>(ldr(base + 0 * 60), ldr(base + 12 * 60));
    R3 X = rop3<OR_>(e1<OR_>(rop3<OR_>(e1<OR_>(G1), G2)), G3);
    X.c &= 0xFFFFFFFFull;
    u64* q = sT2 + s * 3; q[0] = X.a; q[1] = X.b; q[2] = X.c;
  }
  __syncthreads();

  if (threadIdx.x < 256) {
    const int s = threadIdx.x;
    const int dd = s >> 4, hh = s & 15;
    const u64* t2 = sT2 + ((dd + 2) * 20 + (hh + 2)) * 3;
    R3 A = ldr(t2);
    A = rop3<OR_>(A, ldr(t2 + 21 * 3)); A = rop3<OR_>(A, ldr(t2 + 19 * 3));
    A = rop3<OR_>(A, ldr(t2 - 19 * 3)); A = rop3<OR_>(A, ldr(t2 - 21 * 3));
    A = rop3<OR_>(A, ldr(t2 + 40 * 3)); A = rop3<OR_>(A, ldr(t2 - 40 * 3));
    A = rop3<OR_>(A, ldr(t2 + 2 * 3));  A = rop3<OR_>(A, ldr(t2 - 2 * 3));
    A.c &= 0xFFFFFFFFull;
    u64* q = sT1 + s * 3;                // T1 dead — OUT tile
    q[0] = A.a; q[1] = A.b; q[2] = A.c;
  }
  __syncthreads();

  for (int q = threadIdx.x; q < 16 * 16 * 40; q += BLKC) {
    const int r = q / 40, j = q % 40;
    const int dd = r >> 4, hh = r & 15;
    const u64 word = sT1[r * 3 + (j >> 4)];
    const unsigned nb = (unsigned)((word >> ((j & 15) * 4)) & 0xFull);
    f4 v;
    v.x = (float)(nb & 1u); v.y = (float)((nb >> 1) & 1u);
    v.z = (float)((nb >> 2) & 1u); v.w = (float)((nb >> 3) & 1u);
    const size_t e = ((size_t)((b * S + d0 + dd) * S + h0 + hh)) * S + j * 4;
    __builtin_nontemporal_store(v, reinterpret_cast<f4*>(out + e));
  }
}

__global__ __launch_bounds__(BLKC) void chain2_k(const u64* __restrict__ src,
                                                 float* __restrict__ out) {
  __shared__ u64 sIN[32 * 32 * 3];
  __shared__ u64 sT1[32 * 20 * 3];
  __shared__ u64 sT2[20 * 20 * 3];
  const int blk = blockIdx.x;
  const int b = blk / 100, tile = blk % 100;
  const int d0 = (tile / 10) * 16, h0 = (tile % 10) * 16;
  // chain2: even batch = erode(AND), odd = dilate(OR)
  if ((b & 1) != 0) chain_body<true >(src, out, b, d0, h0, sIN, sT1, sT2);
  else              chain_body<false>(src, out, b, d0, h0, sIN, sT1, sT2);
}

extern "C" void kernel_launch(void* const* d_in, const int* in_sizes, int n_in,
                              void* d_out, int out_size, void* d_ws, size_t ws_size,
                              hipStream_t stream) {
  (void)in_sizes; (void)n_in; (void)out_size; (void)ws_size;
  const float* inp = (const float*)d_in[0];
  const float* aux = (const float*)d_in[1];
  float* out = (float*)d_out;

  u64* bufA = (u64*)d_ws;
  u64* bufB = bufA + BUFW;

  packp1_k<<<NB * S, 256, 0, stream>>>(aux, inp, bufA, bufB);   // 640 blocks: pack + P1
  p23_k<<<NB * 100, BLKC, 0, stream>>>(bufA, bufB);             // chain1 P2+P3 -> bits
  chain2_k<<<NB * 100, BLKC, 0, stream>>>(bufB, out);           // chain2 + unpack -> floats
}

// Round 12
// 47.517 us; speedup vs baseline: 1.1081x; 1.1081x over previous
//
#include <hip/hip_runtime.h>
#include <cstdint>

typedef unsigned long long u64;
typedef float f4 __attribute__((ext_vector_type(4)));

constexpr int S   = 160;          // D = H = W
constexpr int NB  = 4;            // batches
constexpr int PAD = 8;            // d/h padding in the global bit buffer (chain reach = 8)
constexpr int SP  = S + 2 * PAD;  // 176
constexpr int BUFW = NB * SP * 3 * SP;     // u64 per buffer (371,712)
constexpr int BLKC = 512;                  // chain kernel block size (8 waves)

__device__ __forceinline__ int widx(int b, int dp, int w, int hp) {
  return ((b * SP + dp) * 3 + w) * SP + hp;
}

// ---------------- full-row (3 u64 = 192 bits) helpers, SoA planes ----------------
struct R3 { u64 a, b, c; };
struct PL { u64 *a, *b, *c;
  __device__ __forceinline__ R3 ld(int i) const { return {a[i], b[i], c[i]}; }
  __device__ __forceinline__ void st(int i, R3 v) const { a[i] = v.a; b[i] = v.b; c[i] = v.c; }
};

template <bool OR_> __device__ __forceinline__ u64 rop(u64 x, u64 y) { return OR_ ? (x | y) : (x & y); }
template <bool OR_> __device__ __forceinline__ R3 rop3(R3 x, R3 y) {
  return {rop<OR_>(x.a, y.a), rop<OR_>(x.b, y.b), rop<OR_>(x.c, y.c)};
}
template <int N> __device__ __forceinline__ R3 sl3(R3 x) {   // toward +k (zeros in)
  return {x.a << N, (x.b << N) | (x.a >> (64 - N)), (x.c << N) | (x.b >> (64 - N))};
}
template <int N> __device__ __forceinline__ R3 sr3(R3 x) {   // toward -k (zeros in)
  return {(x.a >> N) | (x.b << (64 - N)), (x.b >> N) | (x.c << (64 - N)), x.c >> N};
}
template <bool OR_> __device__ __forceinline__ R3 e1(R3 x) { // expand/shrink 1 along k
  return rop3<OR_>(rop3<OR_>(x, sl3<1>(x)), sr3<1>(x));
}

// ---------------- fused 3-pass chain over SoA LDS tiles ----------------
// Tile 16x16. IN 32x32 (halo 8), T1 32x20, T2 20x20.
// P1 (jk): |dj|<=4 -> k±6 ; |dj|=5 -> ±5 ; |dj|=6 -> ±4
// P2 (ik): |di|<=4 -> k±2 ; |di|=5 -> ±1 ; |di|=6 -> 0
// P3 (ij-diamond): (0,0),(±1,±1),(±2,0),(0,±2)
template <bool OR_, bool TOOUT>
__device__ void chain_body(const u64* __restrict__ src, u64* __restrict__ dstBits,
                           float* __restrict__ out, int b, int d0, int h0,
                           PL IN, PL T1, PL T2) {
  // load IN: w outermost so each wave's branch is uniform; consecutive tid -> consecutive hi
  for (int i = threadIdx.x; i < 3 * 32 * 32; i += BLKC) {
    const int hi = i % 32, di = (i / 32) % 32, w = i / 1024;
    const u64 v = src[widx(b, d0 + di, w, h0 + hi)];
    const int o = di * 32 + hi;
    if (w == 0) IN.a[o] = v; else if (w == 1) IN.b[o] = v; else IN.c[o] = v;
  }
  __syncthreads();

  // P1: out d:[-8..23] x h:[-2..17] -> T1[32][20]; IN col = hh + r, r in [0..12]
  for (int s = threadIdx.x; s < 32 * 20; s += BLKC) {
    const int dd = s / 20, hh = s % 20;
    const int o = dd * 32 + hh;
    R3 G1 = IN.ld(o + 2);
#pragma unroll
    for (int r = 3; r <= 10; ++r) G1 = rop3<OR_>(G1, IN.ld(o + r));
    R3 G2 = rop3<OR_>(IN.ld(o + 1), IN.ld(o + 11));
    R3 G3 = rop3<OR_>(IN.ld(o + 0), IN.ld(o + 12));
    R3 X = rop3<OR_>(rop3<OR_>(e1<OR_>(e1<OR_>(G1)), e1<OR_>(G2)), G3);
    R3 y = e1<OR_>(X);
    R3 R = rop3<OR_>(rop3<OR_>(y, sl3<3>(y)), sr3<3>(y));
    R.c &= 0xFFFFFFFFull;
    T1.st(s, R);
  }
  __syncthreads();

  // P2: out d:[-2..17] x h:[-2..17] -> T2[20][20]; T1 row = dd + r
  for (int s = threadIdx.x; s < 20 * 20; s += BLKC) {
    const int dd = s / 20, hh = s % 20;
    R3 G1 = T1.ld((dd + 2) * 20 + hh);
#pragma unroll
    for (int r = 3; r <= 10; ++r) G1 = rop3<OR_>(G1, T1.ld((dd + r) * 20 + hh));
    R3 G2 = rop3<OR_>(T1.ld((dd + 1) * 20 + hh), T1.ld((dd + 11) * 20 + hh));
    R3 G3 = rop3<OR_>(T1.ld((dd + 0) * 20 + hh), T1.ld((dd + 12) * 20 + hh));
    R3 X = rop3<OR_>(e1<OR_>(rop3<OR_>(e1<OR_>(G1), G2)), G3);
    X.c &= 0xFFFFFFFFull;
    T2.st(s, X);
  }
  __syncthreads();

  // P3: final 16x16; T2 center (dd+2, hh+2)
  if (threadIdx.x < 256) {
    const int s = threadIdx.x;
    const int dd = s >> 4, hh = s & 15;
    const int c = (dd + 2) * 20 + (hh + 2);
    R3 A = T2.ld(c);
    A = rop3<OR_>(A, T2.ld(c + 21)); A = rop3<OR_>(A, T2.ld(c + 19));
    A = rop3<OR_>(A, T2.ld(c - 19)); A = rop3<OR_>(A, T2.ld(c - 21));
    A = rop3<OR_>(A, T2.ld(c + 40)); A = rop3<OR_>(A, T2.ld(c - 40));
    A = rop3<OR_>(A, T2.ld(c + 2));  A = rop3<OR_>(A, T2.ld(c - 2));
    A.c &= 0xFFFFFFFFull;
    if (TOOUT) {
      T1.st(s, A);                       // T1 dead after P2 — reuse as OUT tile
    } else {
      dstBits[widx(b, d0 + dd + PAD, 0, h0 + hh + PAD)] = A.a;
      dstBits[widx(b, d0 + dd + PAD, 1, h0 + hh + PAD)] = A.b;
      dstBits[widx(b, d0 + dd + PAD, 2, h0 + hh + PAD)] = A.c;
    }
  }
  if (TOOUT) {
    __syncthreads();
    // unpack OUT tile: 256 rows x 40 f4; LDS reads are wave-broadcast
    for (int q = threadIdx.x; q < 16 * 16 * 40; q += BLKC) {
      const int r = q / 40, j = q % 40;
      const int dd = r >> 4, hh = r & 15;
      const int jw = j >> 4;
      const u64 word = (jw == 0) ? T1.a[r] : ((jw == 1) ? T1.b[r] : T1.c[r]);
      const unsigned nb = (unsigned)((word >> ((j & 15) * 4)) & 0xFull);
      f4 v;
      v.x = (float)(nb & 1u); v.y = (float)((nb >> 1) & 1u);
      v.z = (float)((nb >> 2) & 1u); v.w = (float)((nb >> 3) & 1u);
      const size_t e = ((size_t)((b * S + d0 + dd) * S + h0 + hh)) * S + j * 4;
      __builtin_nontemporal_store(v, reinterpret_cast<f4*>(out + e));
    }
  }
}

// PH0: first chain (even batch => OR/dilate). TOOUT: emit floats (second chain).
template <bool PH0, bool TOOUT>
__global__ __launch_bounds__(BLKC) void chain_k(const u64* __restrict__ src,
                                                u64* __restrict__ dstBits,
                                                float* __restrict__ out) {
  __shared__ u64 sINa[32 * 32], sINb[32 * 32], sINc[32 * 32];   // 3 x 8192 B
  __shared__ u64 sT1a[32 * 20], sT1b[32 * 20], sT1c[32 * 20];   // 3 x 5120 B
  __shared__ u64 sT2a[20 * 20], sT2b[20 * 20], sT2c[20 * 20];   // 3 x 3200 B  => 49,536 B total
  PL IN{sINa, sINb, sINc}, T1{sT1a, sT1b, sT1c}, T2{sT2a, sT2b, sT2c};
  const int blk = blockIdx.x;
  const int b = blk / 100, tile = blk % 100;
  const int d0 = (tile / 10) * 16, h0 = (tile % 10) * 16;
  const bool isor = (((b & 1) == 0) == PH0);
  if (isor) chain_body<true , TOOUT>(src, dstBits, out, b, d0, h0, IN, T1, T2);
  else      chain_body<false, TOOUT>(src, dstBits, out, b, d0, h0, IN, T1, T2);
}

// ---------------- pack: f4 aux -> nibbles in LDS -> u64 words (+ pad zeroing) ----------------
__device__ __forceinline__ u64 squash(u64 x) {  // 8 bytes of nibbles -> 32 bits
  x = (x | (x >> 4))  & 0x00FF00FF00FF00FFull;
  x = (x | (x >> 8))  & 0x0000FFFF0000FFFFull;
  x = (x | (x >> 16)) & 0x00000000FFFFFFFFull;
  return x;
}

__global__ __launch_bounds__(320) void pack_k(const float* __restrict__ aux,
                                              const float* __restrict__ inp,
                                              u64* __restrict__ dstA,
                                              u64* __restrict__ dstB) {
  // zero the pad halo of both buffers (disjoint from interior writes below)
  {
    const int g = blockIdx.x * 320 + threadIdx.x;
    if (g < BUFW) {
      const int hp = g % SP;
      const int dp = (g / (SP * 3)) % SP;
      if ((dp < PAD) | (dp >= S + PAD) | (hp < PAD) | (hp >= S + PAD)) {
        dstA[g] = 0ull; dstB[g] = 0ull;
      }
    }
  }
  __shared__ unsigned char nib[8][48];
  const int r   = threadIdx.x / 40;   // 8 rows per block
  const int pos = threadIdx.x % 40;   // 4 elements each
  const int row = blockIdx.x * 8 + r;
  const size_t ebase = (size_t)row * S + pos * 4;

  const f4 a = __builtin_nontemporal_load(reinterpret_cast<const f4*>(aux) + (row * 40 + pos));
  unsigned n = 0;
  if (a.x < 0.0f) n |= 1u; else if (a.x == 0.0f) { if (inp[ebase + 0] != 0.0f) n |= 1u; }
  if (a.y < 0.0f) n |= 2u; else if (a.y == 0.0f) { if (inp[ebase + 1] != 0.0f) n |= 2u; }
  if (a.z < 0.0f) n |= 4u; else if (a.z == 0.0f) { if (inp[ebase + 2] != 0.0f) n |= 4u; }
  if (a.w < 0.0f) n |= 8u; else if (a.w == 0.0f) { if (inp[ebase + 3] != 0.0f) n |= 8u; }
  nib[r][pos] = (unsigned char)n;
  if (threadIdx.x < 64) nib[threadIdx.x >> 3][40 + (threadIdx.x & 7)] = 0;
  __syncthreads();

  if (threadIdx.x < 24) {
    const int rr = threadIdx.x & 7;
    const int w  = threadIdx.x >> 3;
    const u64 x0 = *reinterpret_cast<const u64*>(&nib[rr][w * 16]);
    const u64 x1 = *reinterpret_cast<const u64*>(&nib[rr][w * 16 + 8]);
    const u64 word = squash(x0) | (squash(x1) << 32);
    const int grow = blockIdx.x * 8 + rr;
    const int h = grow % S, d = (grow / S) % S, b = grow / (S * S);
    dstA[widx(b, d + PAD, w, h + PAD)] = word;
  }
}

extern "C" void kernel_launch(void* const* d_in, const int* in_sizes, int n_in,
                              void* d_out, int out_size, void* d_ws, size_t ws_size,
                              hipStream_t stream) {
  (void)in_sizes; (void)n_in; (void)out_size; (void)ws_size;
  const float* inp = (const float*)d_in[0];
  const float* aux = (const float*)d_in[1];
  float* out = (float*)d_out;

  u64* bufA = (u64*)d_ws;
  u64* bufB = bufA + BUFW;

  const int ROWS = NB * S * S;            // 102400
  pack_k<<<ROWS / 8, 320, 0, stream>>>(aux, inp, bufA, bufB);   // 12800 blocks

  const int CG = NB * 100;                // 400 tile blocks
  chain_k<true , false><<<CG, BLKC, 0, stream>>>(bufA, bufB, out);  // chain 1 -> bits
  chain_k<false, true ><<<CG, BLKC, 0, stream>>>(bufB, bufA, out);  // chain 2 -> floats
}